// Round 6
// baseline (96.453 us; speedup 1.0000x reference)
//
#include <hip/hip_runtime.h>

#define NB 8192
#define ND 128
#define NC 1000
#define NS 32          // j-slices
#define JS (NB / NS)   // 256 j per slice
#define NT (JS / 16)   // 16 b-tiles of 16 j each

typedef __attribute__((ext_vector_type(8))) short bf16x8;
typedef __attribute__((ext_vector_type(4))) float f32x4;

__device__ __forceinline__ unsigned short f2bf(float f) {
    unsigned int u = __float_as_uint(f);
    return (unsigned short)((u + 0x7fffu + ((u >> 16) & 1u)) >> 16);
}

// ---------------- CE (label smoothing) fused with emb->bf16 conversion ----------------
__global__ __launch_bounds__(256) void ce_prep_kernel(const float* __restrict__ logits,
                                                      const float* __restrict__ emb,
                                                      const int* __restrict__ labels,
                                                      unsigned short* __restrict__ ebf,
                                                      float* __restrict__ cls_part) {
    int wave = threadIdx.x >> 6, lane = threadIdx.x & 63;
    int r = blockIdx.x * 4 + wave;

    {
        const float* erow = emb + (size_t)r * ND;
        float2 v = *(const float2*)(erow + lane * 2);
        unsigned int packed = (unsigned int)f2bf(v.x) | ((unsigned int)f2bf(v.y) << 16);
        *(unsigned int*)(ebf + (size_t)r * ND + lane * 2) = packed;
    }

    const float* x = logits + (size_t)r * NC;
    float4 q0 = *(const float4*)(x + 4 * lane);
    float4 q1 = *(const float4*)(x + 256 + 4 * lane);
    float4 q2 = *(const float4*)(x + 512 + 4 * lane);
    float4 q3;
    bool a3 = (192 + lane) < 250;
    if (a3) q3 = *(const float4*)(x + 768 + 4 * lane);
    else q3 = make_float4(-3.4e38f, -3.4e38f, -3.4e38f, -3.4e38f);

    float m = fmaxf(fmaxf(fmaxf(q0.x, q0.y), fmaxf(q0.z, q0.w)),
                    fmaxf(fmaxf(q1.x, q1.y), fmaxf(q1.z, q1.w)));
    m = fmaxf(m, fmaxf(fmaxf(q2.x, q2.y), fmaxf(q2.z, q2.w)));
    m = fmaxf(m, fmaxf(fmaxf(q3.x, q3.y), fmaxf(q3.z, q3.w)));
    float s = (q0.x + q0.y + q0.z + q0.w) + (q1.x + q1.y + q1.z + q1.w) +
              (q2.x + q2.y + q2.z + q2.w) +
              (a3 ? (q3.x + q3.y + q3.z + q3.w) : 0.f);
#pragma unroll
    for (int o = 32; o >= 1; o >>= 1) {
        m = fmaxf(m, __shfl_xor(m, o));
        s += __shfl_xor(s, o);
    }
    float se = expf(q0.x - m) + expf(q0.y - m) + expf(q0.z - m) + expf(q0.w - m) +
               expf(q1.x - m) + expf(q1.y - m) + expf(q1.z - m) + expf(q1.w - m) +
               expf(q2.x - m) + expf(q2.y - m) + expf(q2.z - m) + expf(q2.w - m) +
               expf(q3.x - m) + expf(q3.y - m) + expf(q3.z - m) + expf(q3.w - m);
#pragma unroll
    for (int o = 32; o >= 1; o >>= 1) se += __shfl_xor(se, o);
    float xl = x[labels[r]];
    float v = (m + logf(se)) - 0.9f * xl - 0.1f * (s * (1.0f / NC));
    if (lane == 0) cls_part[r] = v;
}

// ---------------- mining: barrier-free, LDS-free; B-frags direct from L2, 2-stage reg pipeline
// grid (NB/128, NS); 4 independent waves/block; wave owns 32 i-rows, sweeps 256 j of its slice.
// Normalized embeddings: d2 ranking == (-dot) ranking; key = monotone-packed(dot) | index.
// pos (farthest positive) = MIN over same-class of key|j        (tie -> smaller j)
// neg (closest negative)  = MAX over diff-class of key|(8191-j) (tie -> smaller j)
__global__ __launch_bounds__(256) void mine_kernel(const unsigned short* __restrict__ ebf,
                                                   const int* __restrict__ labels,
                                                   uint2* __restrict__ part) {
    int tid = threadIdx.x;
    int wave = tid >> 6, lane = tid & 63;
    int col = lane & 15, grp = lane >> 4;
    int ib = blockIdx.x * 128 + wave * 32;
    int s = blockIdx.y, jbase = s * JS;

    // A fragments: 2 i-tiles x 4 k-chunks, registers for whole kernel
    bf16x8 af0[4], af1[4];
    {
        const unsigned short* a0 = ebf + (size_t)(ib + col) * ND + (grp << 3);
        const unsigned short* a1 = a0 + 16 * ND;
#pragma unroll
        for (int c = 0; c < 4; ++c) {
            af0[c] = *(const bf16x8*)(a0 + c * 32);
            af1[c] = *(const bf16x8*)(a1 + c * 32);
        }
    }
    int li[8];
#pragma unroll
    for (int a = 0; a < 2; ++a)
#pragma unroll
        for (int r = 0; r < 4; ++r) li[a * 4 + r] = labels[ib + a * 16 + grp * 4 + r];

    unsigned bp_[8], bn_[8];
#pragma unroll
    for (int k = 0; k < 8; ++k) { bp_[k] = 0xFFFFFFFFu; bn_[k] = 0u; }

    // lane-fixed base pointers: row (jbase+col), k-bytes at grp*16
    const unsigned short* bptr = ebf + (size_t)(jbase + col) * ND + (grp << 3);
    const int* lbp = labels + jbase + col;

#define LOADB(B, LJ, T)                                                        \
    do {                                                                       \
        const unsigned short* _bp = bptr + (size_t)(T) * (16 * ND);            \
        _Pragma("unroll")                                                      \
        for (int c = 0; c < 4; ++c) B[c] = *(const bf16x8*)(_bp + c * 32);     \
        LJ = lbp[(T) * 16];                                                    \
    } while (0)

#define COMPUTE(B, LJ, T)                                                      \
    do {                                                                       \
        f32x4 x0 = {0.f, 0.f, 0.f, 0.f}, y0 = {0.f, 0.f, 0.f, 0.f};            \
        f32x4 x1 = {0.f, 0.f, 0.f, 0.f}, y1 = {0.f, 0.f, 0.f, 0.f};            \
        x0 = __builtin_amdgcn_mfma_f32_16x16x32_bf16(af0[0], B[0], x0, 0, 0, 0); \
        x1 = __builtin_amdgcn_mfma_f32_16x16x32_bf16(af1[0], B[0], x1, 0, 0, 0); \
        y0 = __builtin_amdgcn_mfma_f32_16x16x32_bf16(af0[2], B[2], y0, 0, 0, 0); \
        y1 = __builtin_amdgcn_mfma_f32_16x16x32_bf16(af1[2], B[2], y1, 0, 0, 0); \
        x0 = __builtin_amdgcn_mfma_f32_16x16x32_bf16(af0[1], B[1], x0, 0, 0, 0); \
        x1 = __builtin_amdgcn_mfma_f32_16x16x32_bf16(af1[1], B[1], x1, 0, 0, 0); \
        y0 = __builtin_amdgcn_mfma_f32_16x16x32_bf16(af0[3], B[3], y0, 0, 0, 0); \
        y1 = __builtin_amdgcn_mfma_f32_16x16x32_bf16(af1[3], B[3], y1, 0, 0, 0); \
        f32x4 acc0 = x0 + y0, acc1 = x1 + y1;                                  \
        int jg = jbase + (T) * 16 + col;                                       \
        unsigned jfp = 8191u - (unsigned)jg;                                   \
        _Pragma("unroll")                                                      \
        for (int r = 0; r < 4; ++r) {                                          \
            unsigned k0 = ((__float_as_uint(acc0[r] + 2.0f) - 0x3F000000u) << 7) & 0xFFFFE000u; \
            bool e0 = (LJ == li[r]);                                           \
            bp_[r] = min(bp_[r], e0 ? (k0 | (unsigned)jg) : 0xFFFFFFFFu);      \
            bn_[r] = max(bn_[r], e0 ? 0u : (k0 | jfp));                        \
            unsigned k1 = ((__float_as_uint(acc1[r] + 2.0f) - 0x3F000000u) << 7) & 0xFFFFE000u; \
            bool e1 = (LJ == li[4 + r]);                                       \
            bp_[4 + r] = min(bp_[4 + r], e1 ? (k1 | (unsigned)jg) : 0xFFFFFFFFu); \
            bn_[4 + r] = max(bn_[4 + r], e1 ? 0u : (k1 | jfp));                \
        }                                                                      \
    } while (0)

    bf16x8 sA[4], sB[4];
    int ljA, ljB;
    LOADB(sA, ljA, 0);
    LOADB(sB, ljB, 1);

    for (int k = 0; k < NT / 2; ++k) {
        int t0 = 2 * k, t1 = 2 * k + 1;
        COMPUTE(sA, ljA, t0);
        {
            int tn = (t0 + 2 < NT) ? t0 + 2 : NT - 1;  // tail: clamped reload, never consumed
            LOADB(sA, ljA, tn);
        }
        COMPUTE(sB, ljB, t1);
        {
            int tn = (t1 + 2 < NT) ? t1 + 2 : NT - 1;
            LOADB(sB, ljB, tn);
        }
    }
#undef LOADB
#undef COMPUTE

    // reduce over the 16 columns (lanes sharing grp): pos=min, neg=max
#pragma unroll
    for (int k = 0; k < 8; ++k) {
#pragma unroll
        for (int msk = 1; msk <= 8; msk <<= 1) {
            bp_[k] = min(bp_[k], (unsigned)__shfl_xor((int)bp_[k], msk));
            bn_[k] = max(bn_[k], (unsigned)__shfl_xor((int)bn_[k], msk));
        }
    }
    if (col == 0) {
#pragma unroll
        for (int a = 0; a < 2; ++a)
#pragma unroll
            for (int r = 0; r < 4; ++r) {
                int gi = ib + a * 16 + grp * 4 + r;
                part[((size_t)gi << 5) + s] = make_uint2(bp_[a * 4 + r], bn_[a * 4 + r]);
            }
    }
}

// ---------------- reduce: merge NS packed partials per row, fp32 hinge, per-row partial -------
__global__ __launch_bounds__(256) void reduce_kernel(const float* __restrict__ e,
                                                     const uint2* __restrict__ part,
                                                     float2* __restrict__ tri_part) {
    int wave = threadIdx.x >> 6, lane = threadIdx.x & 63;
    int r = blockIdx.x * 4 + wave;

    uint2 q = part[((size_t)r << 5) + (lane & 31)];
    unsigned bp = q.x, bn = q.y;
#pragma unroll
    for (int msk = 1; msk <= 16; msk <<= 1) {
        bp = min(bp, (unsigned)__shfl_xor((int)bp, msk));
        bn = max(bn, (unsigned)__shfl_xor((int)bn, msk));
    }
    int jp = (int)(bp & 8191u);
    int jn = 8191 - (int)(bn & 8191u);
    bool valid = (bp != 0xFFFFFFFFu) && (jp != r) && (bn != 0u);

    const float* a = e + (size_t)r * ND;
    const float* p = e + (size_t)jp * ND;
    const float* n = e + (size_t)jn * ND;
    float2 av = *(const float2*)(a + lane * 2);
    float2 pv = *(const float2*)(p + lane * 2);
    float2 nv = *(const float2*)(n + lane * 2);
    float d, sap = 0.f, san = 0.f;
    d = av.x - pv.x + 1e-6f; sap += d * d;
    d = av.y - pv.y + 1e-6f; sap += d * d;
    d = av.x - nv.x + 1e-6f; san += d * d;
    d = av.y - nv.y + 1e-6f; san += d * d;
#pragma unroll
    for (int o = 32; o >= 1; o >>= 1) {
        sap += __shfl_xor(sap, o);
        san += __shfl_xor(san, o);
    }
    if (lane == 0) {
        float per = valid ? fmaxf(sqrtf(sap) - sqrtf(san) + 0.5f, 0.0f) : 0.f;
        tri_part[r] = make_float2(per, valid ? 1.f : 0.f);
    }
}

// ---------------- final combine: single block tree-reduces all partials ----------------
__global__ __launch_bounds__(1024) void fin_kernel(const float* __restrict__ cls_part,
                                                   const float2* __restrict__ tri_part,
                                                   float* __restrict__ out) {
    __shared__ float sc[16], sp[16], sn[16];
    int t = threadIdx.x;
    int wave = t >> 6, lane = t & 63;
    float c = 0.f, tp = 0.f, tc = 0.f;
    for (int k = t; k < NB; k += 1024) {
        c += cls_part[k];
        float2 q = tri_part[k];
        tp += q.x;
        tc += q.y;
    }
#pragma unroll
    for (int o = 32; o >= 1; o >>= 1) {
        c += __shfl_xor(c, o);
        tp += __shfl_xor(tp, o);
        tc += __shfl_xor(tc, o);
    }
    if (lane == 0) { sc[wave] = c; sp[wave] = tp; sn[wave] = tc; }
    __syncthreads();
    if (t == 0) {
        float C = 0.f, P = 0.f, V = 0.f;
        for (int w = 0; w < 16; ++w) { C += sc[w]; P += sp[w]; V += sn[w]; }
        float cls = C * (1.0f / NB);
        float tri = V > 0.5f ? P / V : 0.0f;
        out[0] = cls + tri;
    }
}

extern "C" void kernel_launch(void* const* d_in, const int* in_sizes, int n_in,
                              void* d_out, int out_size, void* d_ws, size_t ws_size,
                              hipStream_t stream) {
    const float* logits = (const float*)d_in[0];
    const float* emb = (const float*)d_in[1];
    const int* labels = (const int*)d_in[2];

    char* w = (char*)d_ws;
    unsigned short* ebf = (unsigned short*)w;                        // NB*ND bf16 (2 MB)
    uint2* part = (uint2*)(w + (size_t)NB * ND * 2);                 // NB*NS uint2 (2 MB)
    float* cls_part = (float*)(w + (size_t)NB * ND * 2 + (size_t)NB * NS * 8);  // NB f32
    float2* tri_part = (float2*)(w + (size_t)NB * ND * 2 + (size_t)NB * NS * 8 + NB * 4);

    ce_prep_kernel<<<NB / 4, 256, 0, stream>>>(logits, emb, labels, ebf, cls_part);
    mine_kernel<<<dim3(NB / 128, NS), 256, 0, stream>>>(ebf, labels, part);
    reduce_kernel<<<NB / 4, 256, 0, stream>>>(emb, part, tri_part);
    fin_kernel<<<1, 1024, 0, stream>>>(cls_part, tri_part, (float*)d_out);
}

// Round 7
// 81.553 us; speedup vs baseline: 1.1827x; 1.1827x over previous
//
#include <hip/hip_runtime.h>

#define NB 8192
#define ND 128
#define NC 1000
#define NS 32          // j-slices
#define JS (NB / NS)   // 256 j per slice
#define NT2 (JS / 32)  // 8 tiles of 32 j per slice

typedef __attribute__((ext_vector_type(8))) short bf16x8;
typedef __attribute__((ext_vector_type(4))) float f32x4;

__device__ __forceinline__ unsigned short f2bf(float f) {
    unsigned int u = __float_as_uint(f);
    return (unsigned short)((u + 0x7fffu + ((u >> 16) & 1u)) >> 16);
}

// ---------------- CE (label smoothing) fused with emb->bf16 conversion ----------------
__global__ __launch_bounds__(256) void ce_prep_kernel(const float* __restrict__ logits,
                                                      const float* __restrict__ emb,
                                                      const int* __restrict__ labels,
                                                      unsigned short* __restrict__ ebf,
                                                      float* __restrict__ cls_part) {
    int wave = threadIdx.x >> 6, lane = threadIdx.x & 63;
    int r = blockIdx.x * 4 + wave;

    {
        const float* erow = emb + (size_t)r * ND;
        float2 v = *(const float2*)(erow + lane * 2);
        unsigned int packed = (unsigned int)f2bf(v.x) | ((unsigned int)f2bf(v.y) << 16);
        *(unsigned int*)(ebf + (size_t)r * ND + lane * 2) = packed;
    }

    const float* x = logits + (size_t)r * NC;
    float4 q0 = *(const float4*)(x + 4 * lane);
    float4 q1 = *(const float4*)(x + 256 + 4 * lane);
    float4 q2 = *(const float4*)(x + 512 + 4 * lane);
    float4 q3;
    bool a3 = (192 + lane) < 250;
    if (a3) q3 = *(const float4*)(x + 768 + 4 * lane);
    else q3 = make_float4(-3.4e38f, -3.4e38f, -3.4e38f, -3.4e38f);

    float m = fmaxf(fmaxf(fmaxf(q0.x, q0.y), fmaxf(q0.z, q0.w)),
                    fmaxf(fmaxf(q1.x, q1.y), fmaxf(q1.z, q1.w)));
    m = fmaxf(m, fmaxf(fmaxf(q2.x, q2.y), fmaxf(q2.z, q2.w)));
    m = fmaxf(m, fmaxf(fmaxf(q3.x, q3.y), fmaxf(q3.z, q3.w)));
    float s = (q0.x + q0.y + q0.z + q0.w) + (q1.x + q1.y + q1.z + q1.w) +
              (q2.x + q2.y + q2.z + q2.w) +
              (a3 ? (q3.x + q3.y + q3.z + q3.w) : 0.f);
#pragma unroll
    for (int o = 32; o >= 1; o >>= 1) {
        m = fmaxf(m, __shfl_xor(m, o));
        s += __shfl_xor(s, o);
    }
    float se = expf(q0.x - m) + expf(q0.y - m) + expf(q0.z - m) + expf(q0.w - m) +
               expf(q1.x - m) + expf(q1.y - m) + expf(q1.z - m) + expf(q1.w - m) +
               expf(q2.x - m) + expf(q2.y - m) + expf(q2.z - m) + expf(q2.w - m) +
               expf(q3.x - m) + expf(q3.y - m) + expf(q3.z - m) + expf(q3.w - m);
#pragma unroll
    for (int o = 32; o >= 1; o >>= 1) se += __shfl_xor(se, o);
    float xl = x[labels[r]];
    float v = (m + logf(se)) - 0.9f * xl - 0.1f * (s * (1.0f / NC));
    if (lane == 0) cls_part[r] = v;
}

// ---------------- mining: neg-only VALUE tracking (3 VALU/dot), 32-j LDS tiles ----------------
// grid (NB/128, NS); 4 waves; wave owns 32 i-rows (A-frags in registers).
// Tracks max dot over diff-class j (value only, no index). Positives handled in reduce.
__global__ __launch_bounds__(256) void mine_kernel(const unsigned short* __restrict__ ebf,
                                                   const int* __restrict__ labels,
                                                   float* __restrict__ part) {
    __shared__ unsigned short btile[3][32 * ND];  // 3 x 8KB
    __shared__ int pj_lb[JS];

    int tid = threadIdx.x;
    int wave = tid >> 6, lane = tid & 63;
    int col = lane & 15, grp = lane >> 4;
    int ib = blockIdx.x * 128 + wave * 32;
    int s = blockIdx.y, jbase = s * JS;

    for (int k = tid; k < JS; k += 256) pj_lb[k] = labels[jbase + k];

    // A fragments: 2 i-tiles x 4 k-chunks, registers for whole kernel
    bf16x8 af0[4], af1[4];
    {
        const unsigned short* a0 = ebf + (size_t)(ib + col) * ND + (grp << 3);
        const unsigned short* a1 = a0 + 16 * ND;
#pragma unroll
        for (int c = 0; c < 4; ++c) {
            af0[c] = *(const bf16x8*)(a0 + c * 32);
            af1[c] = *(const bf16x8*)(a1 + c * 32);
        }
    }
    int li[8];
#pragma unroll
    for (int a = 0; a < 2; ++a)
#pragma unroll
        for (int r = 0; r < 4; ++r) li[a * 4 + r] = labels[ib + a * 16 + grp * 4 + r];

    float bn_[8];
#pragma unroll
    for (int k = 0; k < 8; ++k) bn_[k] = -3.4e38f;

    // STAGE: 32 rows (8KB) per tile = 2 global_load_lds_dwordx4 issues per thread.
    // XOR-swizzled source, linear LDS dest (rule #21).
#define STAGE(buf, jb)                                                                 \
    do {                                                                               \
        const unsigned short* _s0 = ebf + (size_t)((jb) + (tid >> 4)) * ND +           \
                                    ((((tid & 15) ^ ((tid >> 4) & 7))) << 3);          \
        __builtin_amdgcn_global_load_lds(                                              \
            (const __attribute__((address_space(1))) unsigned int*)_s0,                \
            (__attribute__((address_space(3))) unsigned int*)(&btile[buf][0] +         \
                                                              ((tid >> 6) << 9)),      \
            16, 0, 0);                                                                 \
        const unsigned short* _s1 = _s0 + 16 * ND;                                     \
        __builtin_amdgcn_global_load_lds(                                              \
            (const __attribute__((address_space(1))) unsigned int*)_s1,                \
            (__attribute__((address_space(3))) unsigned int*)(&btile[buf][0] + 2048 +  \
                                                              ((tid >> 6) << 9)),      \
            16, 0, 0);                                                                 \
    } while (0)

    // one 16-j sub-tile: swizzled ds_read -> 8 MFMA -> 24 VALU of neg tracking
#define SUBTILE(bt, jl0)                                                               \
    do {                                                                               \
        int lj = pj_lb[(jl0) + col];                                                   \
        bf16x8 bfr[4];                                                                 \
        _Pragma("unroll")                                                              \
        for (int c = 0; c < 4; ++c) {                                                  \
            int chunk = (grp + 4 * c) ^ (col & 7);                                     \
            bfr[c] = *(const bf16x8*)((bt) + col * ND + chunk * 8);                    \
        }                                                                              \
        f32x4 a0 = {0.f, 0.f, 0.f, 0.f}, a1 = {0.f, 0.f, 0.f, 0.f};                    \
        _Pragma("unroll")                                                              \
        for (int c = 0; c < 4; ++c) {                                                  \
            a0 = __builtin_amdgcn_mfma_f32_16x16x32_bf16(af0[c], bfr[c], a0, 0, 0, 0); \
            a1 = __builtin_amdgcn_mfma_f32_16x16x32_bf16(af1[c], bfr[c], a1, 0, 0, 0); \
        }                                                                              \
        _Pragma("unroll")                                                              \
        for (int r = 0; r < 4; ++r) {                                                  \
            bn_[r] = fmaxf(bn_[r], (lj == li[r]) ? -3.4e38f : a0[r]);                  \
            bn_[4 + r] = fmaxf(bn_[4 + r], (lj == li[4 + r]) ? -3.4e38f : a1[r]);      \
        }                                                                              \
    } while (0)

    STAGE(0, jbase);
    STAGE(1, jbase + 32);
    __syncthreads();  // prologue full drain: btile0/1 + pj_lb published

    for (int jt = 0; jt < NT2; ++jt) {
        int cur = jt % 3;
        if (jt + 2 < NT2) STAGE((jt + 2) % 3, jbase + (jt + 2) * 32);

        const unsigned short* bt = &btile[cur][0];
        SUBTILE(bt, jt * 32);
        SUBTILE(bt + 2048, jt * 32 + 16);

        // publish buf[jt+1]: wait for my STAGE(jt+1) (2 instrs); leave STAGE(jt+2) in flight
        if (jt + 2 < NT2) {
            asm volatile("s_waitcnt vmcnt(2)" ::: "memory");
            __builtin_amdgcn_sched_barrier(0);
            __builtin_amdgcn_s_barrier();
        } else if (jt + 1 < NT2) {
            asm volatile("s_waitcnt vmcnt(0)" ::: "memory");
            __builtin_amdgcn_sched_barrier(0);
            __builtin_amdgcn_s_barrier();
        }
    }
#undef STAGE
#undef SUBTILE

    // max over the 16 columns (lanes sharing grp)
#pragma unroll
    for (int k = 0; k < 8; ++k) {
#pragma unroll
        for (int msk = 1; msk <= 8; msk <<= 1)
            bn_[k] = fmaxf(bn_[k], __shfl_xor(bn_[k], msk));
    }
    if (col == 0) {
#pragma unroll
        for (int a = 0; a < 2; ++a)
#pragma unroll
            for (int r = 0; r < 4; ++r) {
                int gi = ib + a * 16 + grp * 4 + r;
                part[((size_t)gi << 5) + s] = bn_[a * 4 + r];
            }
    }
}

// ---------------- reduce: neg from mined value; pos exact via label scan ----------------
// one wave per row. Scans the 32KB label array (L1-hot) to find the ~8 same-class rows,
// computes exact fp32 d2 for them (argmax, first-occurrence ties), then torch-eps norms.
__global__ __launch_bounds__(256) void reduce_kernel(const float* __restrict__ e,
                                                     const int* __restrict__ labels,
                                                     const float* __restrict__ part,
                                                     float2* __restrict__ tri_part) {
    int wave = threadIdx.x >> 6, lane = threadIdx.x & 63;
    int r = blockIdx.x * 4 + wave;

    // merge 32 neg partials (value-only max)
    float nb = part[((size_t)r << 5) + (lane & 31)];
#pragma unroll
    for (int o = 1; o <= 16; o <<= 1) nb = fmaxf(nb, __shfl_xor(nb, o));
    float d_an = sqrtf(fmaxf(2.0f - 2.0f * nb, 0.0f));

    int myl = labels[r];
    const float* a = e + (size_t)r * ND;
    float2 av = *(const float2*)(a + lane * 2);

    float best = -1.0f;
    int jp = r, cnt = 0;
    for (int k = 0; k < NB; k += 64) {
        int j = k + lane;
        bool hit = (labels[j] == myl) && (j != r);
        unsigned long long m = __ballot(hit);
        cnt += (int)__popcll(m);
        while (m) {
            int j2 = k + (int)__builtin_ctzll(m);
            m &= m - 1;
            const float* p = e + (size_t)j2 * ND;
            float2 pv = *(const float2*)(p + lane * 2);
            float dx = av.x - pv.x, dy = av.y - pv.y;
            float ss = dx * dx + dy * dy;
#pragma unroll
            for (int o = 32; o >= 1; o >>= 1) ss += __shfl_xor(ss, o);
            if (ss > best) { best = ss; jp = j2; }  // ascending scan + strict > == first occurrence
        }
    }
    bool valid = (cnt > 0) && (cnt + 1 < NB);

    // winner recomputed with torch's +eps inside the norm (jp==r when no match: safe, unused)
    const float* p = e + (size_t)jp * ND;
    float2 pv = *(const float2*)(p + lane * 2);
    float dx = av.x - pv.x + 1e-6f, dy = av.y - pv.y + 1e-6f;
    float ss = dx * dx + dy * dy;
#pragma unroll
    for (int o = 32; o >= 1; o >>= 1) ss += __shfl_xor(ss, o);
    float d_ap = sqrtf(ss);

    if (lane == 0) {
        float per = valid ? fmaxf(d_ap - d_an + 0.5f, 0.0f) : 0.0f;
        tri_part[r] = make_float2(per, valid ? 1.0f : 0.0f);
    }
}

// ---------------- final combine: single block tree-reduces all partials ----------------
__global__ __launch_bounds__(1024) void fin_kernel(const float* __restrict__ cls_part,
                                                   const float2* __restrict__ tri_part,
                                                   float* __restrict__ out) {
    __shared__ float sc[16], sp[16], sn[16];
    int t = threadIdx.x;
    int wave = t >> 6, lane = t & 63;
    float c = 0.f, tp = 0.f, tc = 0.f;
    for (int k = t; k < NB; k += 1024) {
        c += cls_part[k];
        float2 q = tri_part[k];
        tp += q.x;
        tc += q.y;
    }
#pragma unroll
    for (int o = 32; o >= 1; o >>= 1) {
        c += __shfl_xor(c, o);
        tp += __shfl_xor(tp, o);
        tc += __shfl_xor(tc, o);
    }
    if (lane == 0) { sc[wave] = c; sp[wave] = tp; sn[wave] = tc; }
    __syncthreads();
    if (t == 0) {
        float C = 0.f, P = 0.f, V = 0.f;
        for (int w = 0; w < 16; ++w) { C += sc[w]; P += sp[w]; V += sn[w]; }
        float cls = C * (1.0f / NB);
        float tri = V > 0.5f ? P / V : 0.0f;
        out[0] = cls + tri;
    }
}

extern "C" void kernel_launch(void* const* d_in, const int* in_sizes, int n_in,
                              void* d_out, int out_size, void* d_ws, size_t ws_size,
                              hipStream_t stream) {
    const float* logits = (const float*)d_in[0];
    const float* emb = (const float*)d_in[1];
    const int* labels = (const int*)d_in[2];

    char* w = (char*)d_ws;
    unsigned short* ebf = (unsigned short*)w;                      // NB*ND bf16 (2 MB)
    float* part = (float*)(w + (size_t)NB * ND * 2);               // NB*NS f32 (1 MB)
    float* cls_part = (float*)(w + (size_t)NB * ND * 2 + (size_t)NB * NS * 4);  // NB f32
    float2* tri_part = (float2*)(w + (size_t)NB * ND * 2 + (size_t)NB * NS * 4 + NB * 4);

    ce_prep_kernel<<<NB / 4, 256, 0, stream>>>(logits, emb, labels, ebf, cls_part);
    mine_kernel<<<dim3(NB / 128, NS), 256, 0, stream>>>(ebf, labels, part);
    reduce_kernel<<<NB / 4, 256, 0, stream>>>(emb, labels, part, tri_part);
    fin_kernel<<<1, 1024, 0, stream>>>(cls_part, tri_part, (float*)d_out);
}

// Round 8
// 70.317 us; speedup vs baseline: 1.3717x; 1.1598x over previous
//
#include <hip/hip_runtime.h>

#define NB 8192
#define ND 128
#define NC 1000
#define NJB 64    // j-blocks (128 j each)
#define JBS 128   // j-rows per block
#define NIS 32    // i-slices (256 i each)
#define CAP 64    // bucket capacity per class

typedef __attribute__((ext_vector_type(8))) short bf16x8;
typedef __attribute__((ext_vector_type(4))) float f32x4;

__device__ __forceinline__ unsigned short f2bf(float f) {
    unsigned int u = __float_as_uint(f);
    return (unsigned short)((u + 0x7fffu + ((u >> 16) & 1u)) >> 16);
}

// ---------------- CE (label smoothing) fused with emb->bf16 conversion ----------------
__global__ __launch_bounds__(256) void ce_prep_kernel(const float* __restrict__ logits,
                                                      const float* __restrict__ emb,
                                                      const int* __restrict__ labels,
                                                      unsigned short* __restrict__ ebf,
                                                      float* __restrict__ cls_part) {
    int wave = threadIdx.x >> 6, lane = threadIdx.x & 63;
    int r = blockIdx.x * 4 + wave;

    {
        const float* erow = emb + (size_t)r * ND;
        float2 v = *(const float2*)(erow + lane * 2);
        unsigned int packed = (unsigned int)f2bf(v.x) | ((unsigned int)f2bf(v.y) << 16);
        *(unsigned int*)(ebf + (size_t)r * ND + lane * 2) = packed;
    }

    const float* x = logits + (size_t)r * NC;
    float4 q0 = *(const float4*)(x + 4 * lane);
    float4 q1 = *(const float4*)(x + 256 + 4 * lane);
    float4 q2 = *(const float4*)(x + 512 + 4 * lane);
    float4 q3;
    bool a3 = (192 + lane) < 250;
    if (a3) q3 = *(const float4*)(x + 768 + 4 * lane);
    else q3 = make_float4(-3.4e38f, -3.4e38f, -3.4e38f, -3.4e38f);

    float m = fmaxf(fmaxf(fmaxf(q0.x, q0.y), fmaxf(q0.z, q0.w)),
                    fmaxf(fmaxf(q1.x, q1.y), fmaxf(q1.z, q1.w)));
    m = fmaxf(m, fmaxf(fmaxf(q2.x, q2.y), fmaxf(q2.z, q2.w)));
    m = fmaxf(m, fmaxf(fmaxf(q3.x, q3.y), fmaxf(q3.z, q3.w)));
    float s = (q0.x + q0.y + q0.z + q0.w) + (q1.x + q1.y + q1.z + q1.w) +
              (q2.x + q2.y + q2.z + q2.w) +
              (a3 ? (q3.x + q3.y + q3.z + q3.w) : 0.f);
#pragma unroll
    for (int o = 32; o >= 1; o >>= 1) {
        m = fmaxf(m, __shfl_xor(m, o));
        s += __shfl_xor(s, o);
    }
    float se = expf(q0.x - m) + expf(q0.y - m) + expf(q0.z - m) + expf(q0.w - m) +
               expf(q1.x - m) + expf(q1.y - m) + expf(q1.z - m) + expf(q1.w - m) +
               expf(q2.x - m) + expf(q2.y - m) + expf(q2.z - m) + expf(q2.w - m) +
               expf(q3.x - m) + expf(q3.y - m) + expf(q3.z - m) + expf(q3.w - m);
#pragma unroll
    for (int o = 32; o >= 1; o >>= 1) se += __shfl_xor(se, o);
    float xl = x[labels[r]];
    float v = (m + logf(se)) - 0.9f * xl - 0.1f * (s * (1.0f / NC));
    if (lane == 0) cls_part[r] = v;
}

// ---------------- bucket: per-class row lists (order nondeterministic, consumers tie-break) ---
__global__ __launch_bounds__(256) void bucket_kernel(const int* __restrict__ labels,
                                                     int* __restrict__ cnt,
                                                     int* __restrict__ lists) {
    int r = blockIdx.x * 256 + threadIdx.x;
    int c = labels[r];
    int slot = atomicAdd(&cnt[c], 1);
    if (slot < CAP) lists[c * CAP + slot] = r;
}

// ---------------- mining: zero-barrier static-LDS; value-only neg tracking ----------------
// grid (NJB, NIS); block stages 128 j-rows once; 4 independent waves x 64 i-rows sweep it.
__global__ __launch_bounds__(256) void mine_kernel(const unsigned short* __restrict__ ebf,
                                                   const int* __restrict__ labels,
                                                   float* __restrict__ part) {
    __shared__ unsigned short btile[JBS * ND];  // 32 KB, static after prologue
    int tid = threadIdx.x;
    int wave = tid >> 6, lane = tid & 63;
    int col = lane & 15, grp = lane >> 4;
    int jblk = blockIdx.x, jbase = jblk * JBS;
    int ibase = blockIdx.y * 256 + wave * 64;

    // stage 128 j-rows: XOR-swizzled global source -> linear LDS dest (rule #21)
#pragma unroll
    for (int rep = 0; rep < 8; ++rep) {
        int row = (tid >> 4) + rep * 16;
        const unsigned short* src =
            ebf + (size_t)(jbase + row) * ND + (((tid & 15) ^ (row & 7)) << 3);
        unsigned short* dst = btile + (size_t)(wave * 4 + rep * 16) * ND;
        __builtin_amdgcn_global_load_lds(
            (const __attribute__((address_space(1))) unsigned int*)src,
            (__attribute__((address_space(3))) unsigned int*)dst, 16, 0, 0);
    }

    // A fragments: 4 i-chunks x 4 k-chunks, registers for whole kernel
    bf16x8 af[4][4];
#pragma unroll
    for (int ic = 0; ic < 4; ++ic) {
        const unsigned short* ap = ebf + (size_t)(ibase + ic * 16 + col) * ND + (grp << 3);
#pragma unroll
        for (int kc = 0; kc < 4; ++kc) af[ic][kc] = *(const bf16x8*)(ap + kc * 32);
    }
    int li[16];
#pragma unroll
    for (int ic = 0; ic < 4; ++ic)
#pragma unroll
        for (int r = 0; r < 4; ++r) li[ic * 4 + r] = labels[ibase + ic * 16 + grp * 4 + r];
    int ljs[8];
#pragma unroll
    for (int st = 0; st < 8; ++st) ljs[st] = labels[jbase + st * 16 + col];

    float bn[16];
#pragma unroll
    for (int k = 0; k < 16; ++k) bn[k] = -3.4e38f;

    __syncthreads();  // the ONLY barrier: stage drained (vmcnt0+lgkm0), waves free-run after

#pragma unroll
    for (int st = 0; st < 8; ++st) {
        bf16x8 bfr[4];
#pragma unroll
        for (int kc = 0; kc < 4; ++kc) {
            int chunk = (grp + 4 * kc) ^ (col & 7);
            bfr[kc] = *(const bf16x8*)(btile + (size_t)(st * 16 + col) * ND + chunk * 8);
        }
        f32x4 acc[4] = {{0.f, 0.f, 0.f, 0.f}, {0.f, 0.f, 0.f, 0.f},
                        {0.f, 0.f, 0.f, 0.f}, {0.f, 0.f, 0.f, 0.f}};
#pragma unroll
        for (int kc = 0; kc < 4; ++kc)
#pragma unroll
            for (int ic = 0; ic < 4; ++ic)
                acc[ic] = __builtin_amdgcn_mfma_f32_16x16x32_bf16(af[ic][kc], bfr[kc],
                                                                  acc[ic], 0, 0, 0);
        int lj = ljs[st];
#pragma unroll
        for (int ic = 0; ic < 4; ++ic)
#pragma unroll
            for (int r = 0; r < 4; ++r)
                bn[ic * 4 + r] =
                    fmaxf(bn[ic * 4 + r], (lj == li[ic * 4 + r]) ? -3.4e38f : acc[ic][r]);
    }

    // max over the 16 columns (lanes sharing grp)
#pragma unroll
    for (int k = 0; k < 16; ++k)
#pragma unroll
        for (int msk = 1; msk <= 8; msk <<= 1)
            bn[k] = fmaxf(bn[k], __shfl_xor(bn[k], msk));
    if (col == 0) {
#pragma unroll
        for (int ic = 0; ic < 4; ++ic)
#pragma unroll
            for (int r = 0; r < 4; ++r) {
                int gi = ibase + ic * 16 + grp * 4 + r;
                part[((size_t)gi << 6) + jblk] = bn[ic * 4 + r];
            }
    }
}

// ---------------- reduce: neg from mined value; pos exact via class bucket ----------------
__global__ __launch_bounds__(256) void reduce_kernel(const float* __restrict__ e,
                                                     const int* __restrict__ labels,
                                                     const float* __restrict__ part,
                                                     const int* __restrict__ cnt,
                                                     const int* __restrict__ lists,
                                                     float2* __restrict__ tri_part) {
    int wave = threadIdx.x >> 6, lane = threadIdx.x & 63;
    int r = blockIdx.x * 4 + wave;

    // merge 64 neg partials (value-only max, fully associative)
    float nb = part[((size_t)r << 6) + lane];
#pragma unroll
    for (int o = 1; o <= 32; o <<= 1) nb = fmaxf(nb, __shfl_xor(nb, o));
    float d_an = sqrtf(fmaxf(2.0f - 2.0f * nb, 0.0f));

    int myl = labels[r];
    int ctot = cnt[myl];
    int n = min(ctot, CAP);
    const float* a = e + (size_t)r * ND;
    float2 av = *(const float2*)(a + lane * 2);

    // exact fp32 argmax over same-class candidates; (d2, smaller-j) tie-break makes the
    // result independent of the bucket's atomic fill order
    float best = -1.0f;
    int jp = r;
    for (int k = 0; k < n; ++k) {
        int j2 = lists[myl * CAP + k];  // wave-uniform
        if (j2 == r) continue;
        const float* p = e + (size_t)j2 * ND;
        float2 pv = *(const float2*)(p + lane * 2);
        float dx = av.x - pv.x, dy = av.y - pv.y;
        float ss = dx * dx + dy * dy;
#pragma unroll
        for (int o = 32; o >= 1; o >>= 1) ss += __shfl_xor(ss, o);
        if (ss > best || (ss == best && j2 < jp)) { best = ss; jp = j2; }
    }
    bool valid = (ctot >= 2) && (ctot < NB);

    // winner recomputed with torch's +eps inside the norm (jp==r when none: unused)
    const float* p = e + (size_t)jp * ND;
    float2 pv = *(const float2*)(p + lane * 2);
    float dx = av.x - pv.x + 1e-6f, dy = av.y - pv.y + 1e-6f;
    float ss = dx * dx + dy * dy;
#pragma unroll
    for (int o = 32; o >= 1; o >>= 1) ss += __shfl_xor(ss, o);
    float d_ap = sqrtf(ss);

    if (lane == 0) {
        float per = valid ? fmaxf(d_ap - d_an + 0.5f, 0.0f) : 0.0f;
        tri_part[r] = make_float2(per, valid ? 1.0f : 0.0f);
    }
}

// ---------------- final combine: single block tree-reduces all partials ----------------
__global__ __launch_bounds__(1024) void fin_kernel(const float* __restrict__ cls_part,
                                                   const float2* __restrict__ tri_part,
                                                   float* __restrict__ out) {
    __shared__ float sc[16], sp[16], sn[16];
    int t = threadIdx.x;
    int wave = t >> 6, lane = t & 63;
    float c = 0.f, tp = 0.f, tc = 0.f;
    for (int k = t; k < NB; k += 1024) {
        c += cls_part[k];
        float2 q = tri_part[k];
        tp += q.x;
        tc += q.y;
    }
#pragma unroll
    for (int o = 32; o >= 1; o >>= 1) {
        c += __shfl_xor(c, o);
        tp += __shfl_xor(tp, o);
        tc += __shfl_xor(tc, o);
    }
    if (lane == 0) { sc[wave] = c; sp[wave] = tp; sn[wave] = tc; }
    __syncthreads();
    if (t == 0) {
        float C = 0.f, P = 0.f, V = 0.f;
        for (int w = 0; w < 16; ++w) { C += sc[w]; P += sp[w]; V += sn[w]; }
        float cls = C * (1.0f / NB);
        float tri = V > 0.5f ? P / V : 0.0f;
        out[0] = cls + tri;
    }
}

extern "C" void kernel_launch(void* const* d_in, const int* in_sizes, int n_in,
                              void* d_out, int out_size, void* d_ws, size_t ws_size,
                              hipStream_t stream) {
    const float* logits = (const float*)d_in[0];
    const float* emb = (const float*)d_in[1];
    const int* labels = (const int*)d_in[2];

    char* w = (char*)d_ws;
    unsigned short* ebf = (unsigned short*)w;                              // 2 MB
    float* part = (float*)(w + (size_t)NB * ND * 2);                       // NB*64 f32 (2 MB)
    float* cls_part = (float*)(w + 4194304);                               // NB f32 (32 KB)
    float2* tri_part = (float2*)(w + 4194304 + 32768);                     // NB f32x2 (64 KB)
    int* cnt = (int*)(w + 4194304 + 32768 + 65536);                        // NC int (4 KB)
    int* lists = (int*)(w + 4194304 + 32768 + 65536 + 4096);               // NC*CAP int (256 KB)

    hipMemsetAsync(cnt, 0, NC * sizeof(int), stream);
    ce_prep_kernel<<<NB / 4, 256, 0, stream>>>(logits, emb, labels, ebf, cls_part);
    bucket_kernel<<<NB / 256, 256, 0, stream>>>(labels, cnt, lists);
    mine_kernel<<<dim3(NJB, NIS), 256, 0, stream>>>(ebf, labels, part);
    reduce_kernel<<<NB / 4, 256, 0, stream>>>(emb, labels, part, cnt, lists, tri_part);
    fin_kernel<<<1, 1024, 0, stream>>>(cls_part, tri_part, (float*)d_out);
}

// Round 9
// 64.822 us; speedup vs baseline: 1.4880x; 1.0848x over previous
//
#include <hip/hip_runtime.h>

#define NB 8192
#define ND 128
#define NC 1000
#define NJB 64    // j-blocks (128 j each)
#define JBS 128   // j-rows per block
#define NIS 32    // i-slices (256 i each)
#define CAP 64    // bucket capacity per class

typedef __attribute__((ext_vector_type(8))) short bf16x8;
typedef __attribute__((ext_vector_type(4))) float f32x4;

__device__ __forceinline__ unsigned short f2bf(float f) {
    unsigned int u = __float_as_uint(f);
    return (unsigned short)((u + 0x7fffu + ((u >> 16) & 1u)) >> 16);
}

// ---------------- CE (label smoothing) fused with emb->bf16 conversion + cnt zeroing ---------
__global__ __launch_bounds__(256) void ce_prep_kernel(const float* __restrict__ logits,
                                                      const float* __restrict__ emb,
                                                      const int* __restrict__ labels,
                                                      unsigned short* __restrict__ ebf,
                                                      float* __restrict__ cls_part,
                                                      int* __restrict__ cnt) {
    int wave = threadIdx.x >> 6, lane = threadIdx.x & 63;
    int r = blockIdx.x * 4 + wave;

    // zero the class-count array (bucket_kernel runs after us in stream order)
    if (blockIdx.x == 0) {
        for (int k = threadIdx.x; k < NC; k += 256) cnt[k] = 0;
    }

    {
        const float* erow = emb + (size_t)r * ND;
        float2 v = *(const float2*)(erow + lane * 2);
        unsigned int packed = (unsigned int)f2bf(v.x) | ((unsigned int)f2bf(v.y) << 16);
        *(unsigned int*)(ebf + (size_t)r * ND + lane * 2) = packed;
    }

    const float* x = logits + (size_t)r * NC;
    float4 q0 = *(const float4*)(x + 4 * lane);
    float4 q1 = *(const float4*)(x + 256 + 4 * lane);
    float4 q2 = *(const float4*)(x + 512 + 4 * lane);
    float4 q3;
    bool a3 = (192 + lane) < 250;
    if (a3) q3 = *(const float4*)(x + 768 + 4 * lane);
    else q3 = make_float4(-3.4e38f, -3.4e38f, -3.4e38f, -3.4e38f);

    float m = fmaxf(fmaxf(fmaxf(q0.x, q0.y), fmaxf(q0.z, q0.w)),
                    fmaxf(fmaxf(q1.x, q1.y), fmaxf(q1.z, q1.w)));
    m = fmaxf(m, fmaxf(fmaxf(q2.x, q2.y), fmaxf(q2.z, q2.w)));
    m = fmaxf(m, fmaxf(fmaxf(q3.x, q3.y), fmaxf(q3.z, q3.w)));
    float s = (q0.x + q0.y + q0.z + q0.w) + (q1.x + q1.y + q1.z + q1.w) +
              (q2.x + q2.y + q2.z + q2.w) +
              (a3 ? (q3.x + q3.y + q3.z + q3.w) : 0.f);
#pragma unroll
    for (int o = 32; o >= 1; o >>= 1) {
        m = fmaxf(m, __shfl_xor(m, o));
        s += __shfl_xor(s, o);
    }
    float se = expf(q0.x - m) + expf(q0.y - m) + expf(q0.z - m) + expf(q0.w - m) +
               expf(q1.x - m) + expf(q1.y - m) + expf(q1.z - m) + expf(q1.w - m) +
               expf(q2.x - m) + expf(q2.y - m) + expf(q2.z - m) + expf(q2.w - m) +
               expf(q3.x - m) + expf(q3.y - m) + expf(q3.z - m) + expf(q3.w - m);
#pragma unroll
    for (int o = 32; o >= 1; o >>= 1) se += __shfl_xor(se, o);
    float xl = x[labels[r]];
    float v = (m + logf(se)) - 0.9f * xl - 0.1f * (s * (1.0f / NC));
    if (lane == 0) cls_part[r] = v;
}

// ---------------- bucket: per-class row lists (order nondeterministic, consumers tie-break) ---
__global__ __launch_bounds__(256) void bucket_kernel(const int* __restrict__ labels,
                                                     int* __restrict__ cnt,
                                                     int* __restrict__ lists) {
    int r = blockIdx.x * 256 + threadIdx.x;
    int c = labels[r];
    int slot = atomicAdd(&cnt[c], 1);
    if (slot < CAP) lists[c * CAP + slot] = r;
}

// ---------------- mining: zero-barrier static-LDS; value-only neg tracking ----------------
// grid (NJB, NIS); block stages 128 j-rows once; 4 independent waves x 64 i-rows sweep it.
__global__ __launch_bounds__(256) void mine_kernel(const unsigned short* __restrict__ ebf,
                                                   const int* __restrict__ labels,
                                                   float* __restrict__ part) {
    __shared__ unsigned short btile[JBS * ND];  // 32 KB, static after prologue
    int tid = threadIdx.x;
    int wave = tid >> 6, lane = tid & 63;
    int col = lane & 15, grp = lane >> 4;
    int jblk = blockIdx.x, jbase = jblk * JBS;
    int ibase = blockIdx.y * 256 + wave * 64;

    // stage 128 j-rows: XOR-swizzled global source -> linear LDS dest (rule #21)
#pragma unroll
    for (int rep = 0; rep < 8; ++rep) {
        int row = (tid >> 4) + rep * 16;
        const unsigned short* src =
            ebf + (size_t)(jbase + row) * ND + (((tid & 15) ^ (row & 7)) << 3);
        unsigned short* dst = btile + (size_t)(wave * 4 + rep * 16) * ND;
        __builtin_amdgcn_global_load_lds(
            (const __attribute__((address_space(1))) unsigned int*)src,
            (__attribute__((address_space(3))) unsigned int*)dst, 16, 0, 0);
    }

    // A fragments: 4 i-chunks x 4 k-chunks, registers for whole kernel
    bf16x8 af[4][4];
#pragma unroll
    for (int ic = 0; ic < 4; ++ic) {
        const unsigned short* ap = ebf + (size_t)(ibase + ic * 16 + col) * ND + (grp << 3);
#pragma unroll
        for (int kc = 0; kc < 4; ++kc) af[ic][kc] = *(const bf16x8*)(ap + kc * 32);
    }
    int li[16];
#pragma unroll
    for (int ic = 0; ic < 4; ++ic)
#pragma unroll
        for (int r = 0; r < 4; ++r) li[ic * 4 + r] = labels[ibase + ic * 16 + grp * 4 + r];
    int ljs[8];
#pragma unroll
    for (int st = 0; st < 8; ++st) ljs[st] = labels[jbase + st * 16 + col];

    float bn[16];
#pragma unroll
    for (int k = 0; k < 16; ++k) bn[k] = -3.4e38f;

    __syncthreads();  // the ONLY barrier: stage drained (vmcnt0+lgkm0), waves free-run after

#pragma unroll
    for (int st = 0; st < 8; ++st) {
        bf16x8 bfr[4];
#pragma unroll
        for (int kc = 0; kc < 4; ++kc) {
            int chunk = (grp + 4 * kc) ^ (col & 7);
            bfr[kc] = *(const bf16x8*)(btile + (size_t)(st * 16 + col) * ND + chunk * 8);
        }
        f32x4 acc[4] = {{0.f, 0.f, 0.f, 0.f}, {0.f, 0.f, 0.f, 0.f},
                        {0.f, 0.f, 0.f, 0.f}, {0.f, 0.f, 0.f, 0.f}};
#pragma unroll
        for (int kc = 0; kc < 4; ++kc)
#pragma unroll
            for (int ic = 0; ic < 4; ++ic)
                acc[ic] = __builtin_amdgcn_mfma_f32_16x16x32_bf16(af[ic][kc], bfr[kc],
                                                                  acc[ic], 0, 0, 0);
        int lj = ljs[st];
#pragma unroll
        for (int ic = 0; ic < 4; ++ic)
#pragma unroll
            for (int r = 0; r < 4; ++r)
                bn[ic * 4 + r] =
                    fmaxf(bn[ic * 4 + r], (lj == li[ic * 4 + r]) ? -3.4e38f : acc[ic][r]);
    }

    // max over the 16 columns (lanes sharing grp)
#pragma unroll
    for (int k = 0; k < 16; ++k)
#pragma unroll
        for (int msk = 1; msk <= 8; msk <<= 1)
            bn[k] = fmaxf(bn[k], __shfl_xor(bn[k], msk));
    if (col == 0) {
#pragma unroll
        for (int ic = 0; ic < 4; ++ic)
#pragma unroll
            for (int r = 0; r < 4; ++r) {
                int gi = ibase + ic * 16 + grp * 4 + r;
                part[((size_t)gi << 6) + jblk] = bn[ic * 4 + r];
            }
    }
}

// ---------------- reduce: neg from mined value; pos exact via class bucket ----------------
__global__ __launch_bounds__(256) void reduce_kernel(const float* __restrict__ e,
                                                     const int* __restrict__ labels,
                                                     const float* __restrict__ part,
                                                     const int* __restrict__ cnt,
                                                     const int* __restrict__ lists,
                                                     float2* __restrict__ tri_part) {
    int wave = threadIdx.x >> 6, lane = threadIdx.x & 63;
    int r = blockIdx.x * 4 + wave;

    // merge 64 neg partials (value-only max, fully associative)
    float nb = part[((size_t)r << 6) + lane];
#pragma unroll
    for (int o = 1; o <= 32; o <<= 1) nb = fmaxf(nb, __shfl_xor(nb, o));
    float d_an = sqrtf(fmaxf(2.0f - 2.0f * nb, 0.0f));

    int myl = labels[r];
    int ctot = cnt[myl];
    int n = min(ctot, CAP);
    const float* a = e + (size_t)r * ND;
    float2 av = *(const float2*)(a + lane * 2);

    // exact fp32 argmax over same-class candidates; (d2, smaller-j) tie-break makes the
    // result independent of the bucket's atomic fill order
    float best = -1.0f;
    int jp = r;
    for (int k = 0; k < n; ++k) {
        int j2 = lists[myl * CAP + k];  // wave-uniform
        if (j2 == r) continue;
        const float* p = e + (size_t)j2 * ND;
        float2 pv = *(const float2*)(p + lane * 2);
        float dx = av.x - pv.x, dy = av.y - pv.y;
        float ss = dx * dx + dy * dy;
#pragma unroll
        for (int o = 32; o >= 1; o >>= 1) ss += __shfl_xor(ss, o);
        if (ss > best || (ss == best && j2 < jp)) { best = ss; jp = j2; }
    }
    bool valid = (ctot >= 2) && (ctot < NB);

    // winner recomputed with torch's +eps inside the norm (jp==r when none: unused)
    const float* p = e + (size_t)jp * ND;
    float2 pv = *(const float2*)(p + lane * 2);
    float dx = av.x - pv.x + 1e-6f, dy = av.y - pv.y + 1e-6f;
    float ss = dx * dx + dy * dy;
#pragma unroll
    for (int o = 32; o >= 1; o >>= 1) ss += __shfl_xor(ss, o);
    float d_ap = sqrtf(ss);

    if (lane == 0) {
        float per = valid ? fmaxf(d_ap - d_an + 0.5f, 0.0f) : 0.0f;
        tri_part[r] = make_float2(per, valid ? 1.0f : 0.0f);
    }
}

// ---------------- final combine: single block tree-reduces all partials ----------------
__global__ __launch_bounds__(1024) void fin_kernel(const float* __restrict__ cls_part,
                                                   const float2* __restrict__ tri_part,
                                                   float* __restrict__ out) {
    __shared__ float sc[16], sp[16], sn[16];
    int t = threadIdx.x;
    int wave = t >> 6, lane = t & 63;
    float c = 0.f, tp = 0.f, tc = 0.f;
    for (int k = t; k < NB; k += 1024) {
        c += cls_part[k];
        float2 q = tri_part[k];
        tp += q.x;
        tc += q.y;
    }
#pragma unroll
    for (int o = 32; o >= 1; o >>= 1) {
        c += __shfl_xor(c, o);
        tp += __shfl_xor(tp, o);
        tc += __shfl_xor(tc, o);
    }
    if (lane == 0) { sc[wave] = c; sp[wave] = tp; sn[wave] = tc; }
    __syncthreads();
    if (t == 0) {
        float C = 0.f, P = 0.f, V = 0.f;
        for (int w = 0; w < 16; ++w) { C += sc[w]; P += sp[w]; V += sn[w]; }
        float cls = C * (1.0f / NB);
        float tri = V > 0.5f ? P / V : 0.0f;
        out[0] = cls + tri;
    }
}

extern "C" void kernel_launch(void* const* d_in, const int* in_sizes, int n_in,
                              void* d_out, int out_size, void* d_ws, size_t ws_size,
                              hipStream_t stream) {
    const float* logits = (const float*)d_in[0];
    const float* emb = (const float*)d_in[1];
    const int* labels = (const int*)d_in[2];

    char* w = (char*)d_ws;
    unsigned short* ebf = (unsigned short*)w;                              // 2 MB
    float* part = (float*)(w + (size_t)NB * ND * 2);                       // NB*64 f32 (2 MB)
    float* cls_part = (float*)(w + 4194304);                               // NB f32 (32 KB)
    float2* tri_part = (float2*)(w + 4194304 + 32768);                     // NB f32x2 (64 KB)
    int* cnt = (int*)(w + 4194304 + 32768 + 65536);                        // NC int (4 KB)
    int* lists = (int*)(w + 4194304 + 32768 + 65536 + 4096);               // NC*CAP int (256 KB)

    ce_prep_kernel<<<NB / 4, 256, 0, stream>>>(logits, emb, labels, ebf, cls_part, cnt);
    bucket_kernel<<<NB / 256, 256, 0, stream>>>(labels, cnt, lists);
    mine_kernel<<<dim3(NJB, NIS), 256, 0, stream>>>(ebf, labels, part);
    reduce_kernel<<<NB / 4, 256, 0, stream>>>(emb, labels, part, cnt, lists, tri_part);
    fin_kernel<<<1, 1024, 0, stream>>>(cls_part, tri_part, (float*)d_out);
}